// Round 8
// baseline (145.820 us; speedup 1.0000x reference)
//
#include <hip/hip_runtime.h>

#define NROWS 12288
#define BSZ   4096
#define DIM   128
#define CSPLIT 16
#define COLS_PER_BLOCK (NROWS / CSPLIT)   // 768
#define NSTRIPS (COLS_PER_BLOCK / 32)     // 24 strips of 32 cols
#define ROWS_PER_BLOCK 256                // 4 waves x 64 rows
#define GRIDX (NROWS / ROWS_PER_BLOCK)    // 48
#define TOTAL_BLOCKS (GRIDX * CSPLIT)     // 768 = 3/CU
#define NMT 4                             // 16-row mtiles per wave

typedef __bf16 bf16x8 __attribute__((ext_vector_type(8)));
typedef float  f32x4  __attribute__((ext_vector_type(4)));

__device__ __forceinline__ unsigned short f2bf(float f) {
  unsigned int u = __float_as_uint(f);
  u = u + 0x7FFFu + ((u >> 16) & 1u);   // round-to-nearest-even
  return (unsigned short)(u >> 16);
}
__device__ __forceinline__ float bf2f(unsigned short h) {
  return __uint_as_float(((unsigned int)h) << 16);
}

// ---------------------------------------------------------------------------
// Kernel 1 (fused prep + posmax): one wave per triplet index i.
// ---------------------------------------------------------------------------
__global__ void prep_k(const float* __restrict__ a, const float* __restrict__ p,
                       const float* __restrict__ nn,
                       unsigned short* __restrict__ embh, float* __restrict__ sq,
                       unsigned int* __restrict__ negbits,
                       float* __restrict__ posmax2, float* __restrict__ regpart,
                       unsigned int* __restrict__ done) {
  if (blockIdx.x == 0 && threadIdx.x == 0) *done = 0u;   // ws is poisoned 0xAA
  const int w = threadIdx.x >> 6, lane = threadIdx.x & 63;
  const int i = blockIdx.x * 4 + w;
  const float2 av = reinterpret_cast<const float2*>(a  + (size_t)i * DIM)[lane];
  const float2 pv = reinterpret_cast<const float2*>(p  + (size_t)i * DIM)[lane];
  const float2 nv = reinterpret_cast<const float2*>(nn + (size_t)i * DIM)[lane];

  const unsigned short ha0 = f2bf(av.x), ha1 = f2bf(av.y);
  const unsigned short hp0 = f2bf(pv.x), hp1 = f2bf(pv.y);
  const unsigned short hn0 = f2bf(nv.x), hn1 = f2bf(nv.y);
  reinterpret_cast<ushort2*>(embh + (size_t)i * DIM)[lane]             = make_ushort2(ha0, ha1);
  reinterpret_cast<ushort2*>(embh + (size_t)(BSZ + i) * DIM)[lane]     = make_ushort2(hp0, hp1);
  reinterpret_cast<ushort2*>(embh + (size_t)(2 * BSZ + i) * DIM)[lane] = make_ushort2(hn0, hn1);

  // sq of ROUNDED values (so the GEMM-based d2 is consistent & >= 0)
  float rax = bf2f(ha0), ray = bf2f(ha1);
  float rpx = bf2f(hp0), rpy = bf2f(hp1);
  float rnx = bf2f(hn0), rny = bf2f(hn1);
  float sa = rax * rax + ray * ray;
  float sp = rpx * rpx + rpy * rpy;
  float sn = rnx * rnx + rny * rny;

  // reg from exact values
  float t0 = fabsf(av.x) - 1.f, t1 = fabsf(av.y) - 1.f;
  float t2 = fabsf(pv.x) - 1.f, t3 = fabsf(pv.y) - 1.f;
  float t4 = fabsf(nv.x) - 1.f, t5 = fabsf(nv.y) - 1.f;
  float rg = t0 * t0 + t1 * t1 + t2 * t2 + t3 * t3 + t4 * t4 + t5 * t5;

  // pos distances, exact fp32
  float dx, dy;
  dx = av.x - pv.x; dy = av.y - pv.y; float dap = dx * dx + dy * dy;
  dx = av.x - nv.x; dy = av.y - nv.y; float dan = dx * dx + dy * dy;
  dx = pv.x - nv.x; dy = pv.y - nv.y; float dpn = dx * dx + dy * dy;

  for (int m = 32; m; m >>= 1) {
    sa  += __shfl_xor(sa, m);  sp  += __shfl_xor(sp, m);  sn  += __shfl_xor(sn, m);
    rg  += __shfl_xor(rg, m);
    dap += __shfl_xor(dap, m); dan += __shfl_xor(dan, m); dpn += __shfl_xor(dpn, m);
  }
  if (lane == 0) {
    sq[i] = sa; sq[BSZ + i] = sp; sq[2 * BSZ + i] = sn;
    negbits[i] = negbits[BSZ + i] = negbits[2 * BSZ + i] = 0x7F800000u;  // +inf
    posmax2[i]           = fmaxf(dap, dan);
    posmax2[BSZ + i]     = fmaxf(dap, dpn);
    posmax2[2 * BSZ + i] = fmaxf(dan, dpn);
    regpart[i] = rg;
  }
}

// ---------------------------------------------------------------------------
// Kernel 2: neg_min^2 = fused E*E^T (bf16 MFMA 16x16x32) + row-min + final
// scalar reduction in the last-finishing block.
// Round-8 = round-5 occupancy (64 rows/wave, 3 blocks/CU, 12 waves/CU —
// perf across rounds tracks wave-count, not pipeline depth) + round-7's
// rolling single-register B-buffer (removes the LDS-phase serialization
// that capped round 5 at MfmaUtil 31%). Register budget at (256,3)'s
// 170-cap: afrag 64 + bfr 32 + acc 32 (AGPR, unified) + minv 16 + temps
// ~20 = ~164. Round 6 spilled because it held TWO B sets at this cap.
// Triple-buffered LDS; stage(c+2) gets a full MFMA phase of vmcnt lead.
// ---------------------------------------------------------------------------
__global__ __launch_bounds__(256, 3) void negmin_k(
    const unsigned short* __restrict__ embh,
    const float* __restrict__ sq,
    unsigned int* __restrict__ negbits,
    const float* __restrict__ posmax2,
    const float* __restrict__ regpart,
    unsigned int* __restrict__ done,
    float* __restrict__ out) {
  __shared__ __align__(16) char ldsB[3][8192];   // [buf][f*1024 + lane*16]
  __shared__ float red[4], redr[4];
  __shared__ int lastFlag;
  const int tid  = threadIdx.x;
  const int w    = tid >> 6;
  const int lane = tid & 63;
  const int c16  = lane & 15;
  const int q    = lane >> 4;
  const int wRow    = blockIdx.x * ROWS_PER_BLOCK + w * 64;  // wave's 64 rows
  const int colBase = blockIdx.y * COLS_PER_BLOCK;
  const int rot     = (blockIdx.x * 5 + blockIdx.y) % NSTRIPS;

  // A fragments: 64 rows x K=128. 4 mtiles x 4 ksteps, A[m=c16][k=q*8+j].
  bf16x8 afrag[NMT][4];
  {
    const char* abase = (const char*)embh + (size_t)(wRow + c16) * 256 + q * 16;
#pragma unroll
    for (int mt = 0; mt < NMT; ++mt)
#pragma unroll
      for (int ks = 0; ks < 4; ++ks)
        afrag[mt][ks] = *reinterpret_cast<const bf16x8*>(abase + mt * 4096 + ks * 64);
  }

  float minv[NMT][4];
#pragma unroll
  for (int mt = 0; mt < NMT; ++mt)
#pragma unroll
    for (int r = 0; r < 4; ++r) minv[mt][r] = __builtin_inff();

  // Stage strip sidx into LDS buffer b: 8 chunks of 1 KB, wave w issues
  // chunks 2w,2w+1. Source per lane chosen so LDS lands in B-fragment order:
  // chunk f=(ks*2+ct) holds B[k=q*8+j][n=ct*16+c16] at lane*16.
  auto stage = [&](int sidx, int b) {
#pragma unroll
    for (int h = 0; h < 2; ++h) {
      const int kc = w * 2 + h;
      const char* gp = (const char*)embh +
          (size_t)(colBase + sidx * 32 + (kc & 1) * 16 + c16) * 256 +
          (kc >> 1) * 64 + q * 16;
      __builtin_amdgcn_global_load_lds(
          (const __attribute__((address_space(1))) unsigned int*)gp,
          (__attribute__((address_space(3))) unsigned int*)(&ldsB[b][kc * 1024]),
          16, 0, 0);
    }
  };

  int strip = rot;                                   // strip index for iter c
  stage(strip, 0);
  { int s1 = strip + 1; if (s1 >= NSTRIPS) s1 -= NSTRIPS; stage(s1, 1); }
  __syncthreads();                                   // strips c=0,1 staged

  // Preload bfr with strip 0 (buf 0).
  bf16x8 bfr[8];
#pragma unroll
  for (int f = 0; f < 8; ++f)
    bfr[f] = *reinterpret_cast<const bf16x8*>(&ldsB[0][f * 1024 + lane * 16]);

  for (int c = 0; c < NSTRIPS; ++c) {
    if (c + 2 < NSTRIPS) {                           // stage strip c+2
      int s2 = strip + 2; if (s2 >= NSTRIPS) s2 -= NSTRIPS;
      stage(s2, (c + 2) % 3);
    }
    const int colStart = colBase + strip * 32;
    const float sq0 = sq[colStart + c16];            // issued early, used post-barrier
    const float sq1 = sq[colStart + 16 + c16];
    const char* nb = ldsB[(c + 1) % 3];              // strip c+1 (certified @ end c-1)

    f32x4 acc[NMT][2] = {};
#pragma unroll
    for (int f = 0; f < 8; ++f) {
      const int ks = f >> 1, ct = f & 1;
      const bf16x8 bb = bfr[f];
#pragma unroll
      for (int mt = 0; mt < NMT; ++mt)
        acc[mt][ct] =
            __builtin_amdgcn_mfma_f32_16x16x32_bf16(afrag[mt][ks], bb, acc[mt][ct], 0, 0, 0);
      if (c + 1 < NSTRIPS)                           // rolling refill for next iter
        bfr[f] = *reinterpret_cast<const bf16x8*>(nb + f * 1024 + lane * 16);
    }

    // Drains stage(c+2) (a full MFMA phase of lead) + refill ds_reads;
    // certifies the buffers for the next iteration.
    __syncthreads();

    // Epilogue on registers. Exclusion j == i (mod 4096): possible only when
    // dd in [0,76) U (4064,4095] for a 64-row x 32-col wave tile.
    const int dd = (colStart - wRow) & 4095;
    if (dd < 76 || dd > 4064) {
#pragma unroll
      for (int mt = 0; mt < NMT; ++mt)
#pragma unroll
        for (int ct = 0; ct < 2; ++ct) {
          const float sqb = ct ? sq1 : sq0;
          const int lvc = dd + ct * 16 + c16 - q * 4;
#pragma unroll
          for (int r = 0; r < 4; ++r) {
            float v = fmaf(-2.f, acc[mt][ct][r], sqb);
            const int K = mt * 16 + r;
            if (lvc == K || lvc == K + 4096) v = __builtin_inff();
            minv[mt][r] = fminf(minv[mt][r], v);
          }
        }
    } else {
#pragma unroll
      for (int mt = 0; mt < NMT; ++mt)
#pragma unroll
        for (int ct = 0; ct < 2; ++ct) {
          const float sqb = ct ? sq1 : sq0;
#pragma unroll
          for (int r = 0; r < 4; ++r)
            minv[mt][r] = fminf(minv[mt][r], fmaf(-2.f, acc[mt][ct][r], sqb));
        }
    }

    strip = strip + 1; if (strip >= NSTRIPS) strip -= NSTRIPS;
  }

  // Per-row finalize: reduce the 16 column-lanes, atomicMin (uint bits are
  // order-preserving for floats >= 0). Distinct addresses per row.
#pragma unroll
  for (int mt = 0; mt < NMT; ++mt)
#pragma unroll
    for (int r = 0; r < 4; ++r) {
      float v = minv[mt][r];
      v = fminf(v, __shfl_xor(v, 1));
      v = fminf(v, __shfl_xor(v, 2));
      v = fminf(v, __shfl_xor(v, 4));
      v = fminf(v, __shfl_xor(v, 8));
      if (c16 == 0) {
        const int row = wRow + mt * 16 + q * 4 + r;   // C/D: row=(lane>>4)*4+r
        float d2 = sq[row] + v;
        d2 = fmaxf(d2, 0.f);
        atomicMin(&negbits[row], __float_as_uint(d2));
      }
    }

  // ---- last-finishing block does the final scalar reduction ----
  __syncthreads();                 // all waves' atomics drained (vmcnt(0))
  if (tid == 0) {
    __threadfence();
    const unsigned int prev = atomicAdd(done, 1u);
    lastFlag = (prev == TOTAL_BLOCKS - 1) ? 1 : 0;
  }
  __syncthreads();                 // lastFlag is block-uniform
  if (lastFlag) {
    float s = 0.f, rg = 0.f;
    for (int i = tid; i < NROWS; i += 256) {
      const float pm = sqrtf(posmax2[i]);
      // Non-destructive coherent read: min(x, +inf) == x, returns old.
      const unsigned int nb2 = atomicMin(&negbits[i], 0x7F800000u);
      s += fmaxf(pm - sqrtf(__uint_as_float(nb2)) + 0.4f, 0.f);
    }
    for (int i = tid; i < BSZ; i += 256) rg += regpart[i];
    for (int m = 32; m; m >>= 1) { s += __shfl_xor(s, m); rg += __shfl_xor(rg, m); }
    if (lane == 0) { red[w] = s; redr[w] = rg; }
    __syncthreads();
    if (tid == 0) {
      const float t  = red[0] + red[1] + red[2] + red[3];
      const float tr = redr[0] + redr[1] + redr[2] + redr[3];
      out[0] = t / (float)NROWS + 0.01f * (tr / (float)(NROWS * DIM));
    }
  }
}

// ---------------------------------------------------------------------------
extern "C" void kernel_launch(void* const* d_in, const int* in_sizes, int n_in,
                              void* d_out, int out_size, void* d_ws, size_t ws_size,
                              hipStream_t stream) {
  const float* a  = (const float*)d_in[0];
  const float* p  = (const float*)d_in[1];
  const float* nn = (const float*)d_in[2];
  float* out = (float*)d_out;
  char* ws = (char*)d_ws;

  const size_t EMBH_BYTES = (size_t)NROWS * DIM * 2;       // 3,145,728
  unsigned short* embh    = (unsigned short*)ws;
  float*          sq      = (float*)(ws + EMBH_BYTES);
  unsigned int*   negbit  = (unsigned int*)(ws + EMBH_BYTES + (size_t)NROWS * 4);
  float*          pos2    = (float*)(ws + EMBH_BYTES + (size_t)NROWS * 8);
  float*          regpart = (float*)(ws + EMBH_BYTES + (size_t)NROWS * 12);
  unsigned int*   done    = (unsigned int*)(ws + EMBH_BYTES + (size_t)NROWS * 12 + (size_t)BSZ * 4);

  prep_k<<<BSZ / 4, 256, 0, stream>>>(a, p, nn, embh, sq, negbit, pos2, regpart, done);
  negmin_k<<<dim3(GRIDX, CSPLIT), 256, 0, stream>>>(embh, sq, negbit, pos2, regpart, done, out);
}

// Round 9
// 135.527 us; speedup vs baseline: 1.0759x; 1.0759x over previous
//
#include <hip/hip_runtime.h>

#define NROWS 12288
#define BSZ   4096
#define DIM   128
#define CSPLIT 16
#define COLS_PER_BLOCK (NROWS / CSPLIT)   // 768
#define NSTRIPS (COLS_PER_BLOCK / 64)     // 12 strips of 64 cols
#define ROWS_PER_BLOCK 256                // 4 waves x 64 rows
#define GRIDX (NROWS / ROWS_PER_BLOCK)    // 48
#define TOTAL_BLOCKS (GRIDX * CSPLIT)     // 768 = 3/CU
#define NMT 4                             // 16-row mtiles per wave

typedef __bf16 bf16x8 __attribute__((ext_vector_type(8)));
typedef float  f32x4  __attribute__((ext_vector_type(4)));

__device__ __forceinline__ unsigned short f2bf(float f) {
  unsigned int u = __float_as_uint(f);
  u = u + 0x7FFFu + ((u >> 16) & 1u);   // round-to-nearest-even
  return (unsigned short)(u >> 16);
}
__device__ __forceinline__ float bf2f(unsigned short h) {
  return __uint_as_float(((unsigned int)h) << 16);
}

// ---------------------------------------------------------------------------
// Kernel 1 (fused prep + posmax): one wave per triplet index i.
// ---------------------------------------------------------------------------
__global__ void prep_k(const float* __restrict__ a, const float* __restrict__ p,
                       const float* __restrict__ nn,
                       unsigned short* __restrict__ embh, float* __restrict__ sq,
                       unsigned int* __restrict__ negbits,
                       float* __restrict__ posmax2, float* __restrict__ regpart,
                       unsigned int* __restrict__ done) {
  if (blockIdx.x == 0 && threadIdx.x == 0) *done = 0u;   // ws is poisoned 0xAA
  const int w = threadIdx.x >> 6, lane = threadIdx.x & 63;
  const int i = blockIdx.x * 4 + w;
  const float2 av = reinterpret_cast<const float2*>(a  + (size_t)i * DIM)[lane];
  const float2 pv = reinterpret_cast<const float2*>(p  + (size_t)i * DIM)[lane];
  const float2 nv = reinterpret_cast<const float2*>(nn + (size_t)i * DIM)[lane];

  const unsigned short ha0 = f2bf(av.x), ha1 = f2bf(av.y);
  const unsigned short hp0 = f2bf(pv.x), hp1 = f2bf(pv.y);
  const unsigned short hn0 = f2bf(nv.x), hn1 = f2bf(nv.y);
  reinterpret_cast<ushort2*>(embh + (size_t)i * DIM)[lane]             = make_ushort2(ha0, ha1);
  reinterpret_cast<ushort2*>(embh + (size_t)(BSZ + i) * DIM)[lane]     = make_ushort2(hp0, hp1);
  reinterpret_cast<ushort2*>(embh + (size_t)(2 * BSZ + i) * DIM)[lane] = make_ushort2(hn0, hn1);

  // sq of ROUNDED values (so the GEMM-based d2 is consistent & >= 0)
  float rax = bf2f(ha0), ray = bf2f(ha1);
  float rpx = bf2f(hp0), rpy = bf2f(hp1);
  float rnx = bf2f(hn0), rny = bf2f(hn1);
  float sa = rax * rax + ray * ray;
  float sp = rpx * rpx + rpy * rpy;
  float sn = rnx * rnx + rny * rny;

  // reg from exact values
  float t0 = fabsf(av.x) - 1.f, t1 = fabsf(av.y) - 1.f;
  float t2 = fabsf(pv.x) - 1.f, t3 = fabsf(pv.y) - 1.f;
  float t4 = fabsf(nv.x) - 1.f, t5 = fabsf(nv.y) - 1.f;
  float rg = t0 * t0 + t1 * t1 + t2 * t2 + t3 * t3 + t4 * t4 + t5 * t5;

  // pos distances, exact fp32
  float dx, dy;
  dx = av.x - pv.x; dy = av.y - pv.y; float dap = dx * dx + dy * dy;
  dx = av.x - nv.x; dy = av.y - nv.y; float dan = dx * dx + dy * dy;
  dx = pv.x - nv.x; dy = pv.y - nv.y; float dpn = dx * dx + dy * dy;

  for (int m = 32; m; m >>= 1) {
    sa  += __shfl_xor(sa, m);  sp  += __shfl_xor(sp, m);  sn  += __shfl_xor(sn, m);
    rg  += __shfl_xor(rg, m);
    dap += __shfl_xor(dap, m); dan += __shfl_xor(dan, m); dpn += __shfl_xor(dpn, m);
  }
  if (lane == 0) {
    sq[i] = sa; sq[BSZ + i] = sp; sq[2 * BSZ + i] = sn;
    negbits[i] = negbits[BSZ + i] = negbits[2 * BSZ + i] = 0x7F800000u;  // +inf
    posmax2[i]           = fmaxf(dap, dan);
    posmax2[BSZ + i]     = fmaxf(dap, dpn);
    posmax2[2 * BSZ + i] = fmaxf(dan, dpn);
    regpart[i] = rg;
  }
}

// ---------------------------------------------------------------------------
// Kernel 2: neg_min^2 = fused E*E^T (bf16 MFMA 16x16x32) + row-min + final
// scalar reduction in the last-finishing block.
// Round-9 = round-5's register profile EXACTLY (B consumed straight from
// LDS, short live ranges, acc 32 AGPR, ~140 unified regs — the only
// structure that has never spilled) with HALF the barrier rounds: 64-col
// strips (16 KB, double-buffered) processed as two sequential 32-col
// sub-tiles inside one barrier round. r5 spent ~2900 cyc/round of fixed
// barrier/skew overhead over 24 rounds; 12 rounds amortize it 2x.
// r6/r7/r8 all lost to register spills or occupancy — do NOT hold B in
// persistent registers at (256,3).
// ---------------------------------------------------------------------------
__global__ __launch_bounds__(256, 3) void negmin_k(
    const unsigned short* __restrict__ embh,
    const float* __restrict__ sq,
    unsigned int* __restrict__ negbits,
    const float* __restrict__ posmax2,
    const float* __restrict__ regpart,
    unsigned int* __restrict__ done,
    float* __restrict__ out) {
  __shared__ __align__(16) char ldsB[2][16384];  // [buf][chunk*1024 + lane*16]
  __shared__ float red[4], redr[4];
  __shared__ int lastFlag;
  const int tid  = threadIdx.x;
  const int w    = tid >> 6;
  const int lane = tid & 63;
  const int c16  = lane & 15;
  const int q    = lane >> 4;
  const int wRow    = blockIdx.x * ROWS_PER_BLOCK + w * 64;  // wave's 64 rows
  const int colBase = blockIdx.y * COLS_PER_BLOCK;
  const int rot     = (blockIdx.x * 5 + blockIdx.y) % NSTRIPS;

  // A fragments: 64 rows x K=128. 4 mtiles x 4 ksteps, A[m=c16][k=q*8+j].
  bf16x8 afrag[NMT][4];
  {
    const char* abase = (const char*)embh + (size_t)(wRow + c16) * 256 + q * 16;
#pragma unroll
    for (int mt = 0; mt < NMT; ++mt)
#pragma unroll
      for (int ks = 0; ks < 4; ++ks)
        afrag[mt][ks] = *reinterpret_cast<const bf16x8*>(abase + mt * 4096 + ks * 64);
  }

  float minv[NMT][4];
#pragma unroll
  for (int mt = 0; mt < NMT; ++mt)
#pragma unroll
    for (int r = 0; r < 4; ++r) minv[mt][r] = __builtin_inff();

  // Stage a 64-col strip (16 KB) into LDS buffer b: 16 chunks of 1 KB,
  // wave w issues chunks 4w..4w+3. Chunk (ks*4+ct) holds the B-fragment
  // B[k=q*8+j][n=ct*16+c16] for kstep ks at offset lane*16.
  auto stage = [&](int sidx, int b) {
#pragma unroll
    for (int h = 0; h < 4; ++h) {
      const int kc = w * 4 + h;
      const char* gp = (const char*)embh +
          (size_t)(colBase + sidx * 64 + (kc & 3) * 16 + c16) * 256 +
          (kc >> 2) * 64 + q * 16;
      __builtin_amdgcn_global_load_lds(
          (const __attribute__((address_space(1))) unsigned int*)gp,
          (__attribute__((address_space(3))) unsigned int*)(&ldsB[b][kc * 1024]),
          16, 0, 0);
    }
  };

  int strip = rot;                                   // strip index for iter c
  stage(strip, 0);
  { int s1 = strip + 1; if (s1 >= NSTRIPS) s1 -= NSTRIPS; stage(s1, 1); }
  __syncthreads();                                   // strips c=0,1 staged

  for (int c = 0; c < NSTRIPS; ++c) {
    const int b = c & 1;
    const char* lb = ldsB[b];
    const int colStart = colBase + strip * 64;

    // ---- sub-tile 0: cols [colStart, colStart+32) ----
    {
      const float sq0 = sq[colStart + c16];
      const float sq1 = sq[colStart + 16 + c16];
      f32x4 acc[NMT][2] = {};
#pragma unroll
      for (int f = 0; f < 8; ++f) {
        const int ks = f >> 1, ct = f & 1;
        const bf16x8 bb =
            *reinterpret_cast<const bf16x8*>(lb + (ks * 4 + ct) * 1024 + lane * 16);
#pragma unroll
        for (int mt = 0; mt < NMT; ++mt)
          acc[mt][ct] =
              __builtin_amdgcn_mfma_f32_16x16x32_bf16(afrag[mt][ks], bb, acc[mt][ct], 0, 0, 0);
      }
      const int dd = (colStart - wRow) & 4095;
      if (dd < 64 || dd > 4064) {
#pragma unroll
        for (int mt = 0; mt < NMT; ++mt)
#pragma unroll
          for (int ct = 0; ct < 2; ++ct) {
            const float sqb = ct ? sq1 : sq0;
            const int lvc = dd + ct * 16 + c16 - q * 4;
#pragma unroll
            for (int r = 0; r < 4; ++r) {
              float v = fmaf(-2.f, acc[mt][ct][r], sqb);
              const int K = mt * 16 + r;
              if (lvc == K || lvc == K + 4096) v = __builtin_inff();
              minv[mt][r] = fminf(minv[mt][r], v);
            }
          }
      } else {
#pragma unroll
        for (int mt = 0; mt < NMT; ++mt)
#pragma unroll
          for (int ct = 0; ct < 2; ++ct) {
            const float sqb = ct ? sq1 : sq0;
#pragma unroll
            for (int r = 0; r < 4; ++r)
              minv[mt][r] = fminf(minv[mt][r], fmaf(-2.f, acc[mt][ct][r], sqb));
          }
      }
    }

    // ---- sub-tile 1: cols [colStart+32, colStart+64) ----
    f32x4 acc[NMT][2] = {};
    {
#pragma unroll
      for (int f = 0; f < 8; ++f) {
        const int ks = f >> 1, ct = 2 + (f & 1);
        const bf16x8 bb =
            *reinterpret_cast<const bf16x8*>(lb + (ks * 4 + ct) * 1024 + lane * 16);
#pragma unroll
        for (int mt = 0; mt < NMT; ++mt)
          acc[mt][f & 1] =
              __builtin_amdgcn_mfma_f32_16x16x32_bf16(afrag[mt][ks], bb, acc[mt][f & 1], 0, 0, 0);
      }
    }

    // One barrier per 64 cols: all waves done reading buf b; drains the
    // stage issued last round; certifies buf b for overwrite.
    __syncthreads();
    if (c + 2 < NSTRIPS) {                           // stage strip c+2
      int s2 = strip + 2; if (s2 >= NSTRIPS) s2 -= NSTRIPS;
      stage(s2, b);
    }

    // Epilogue of sub-tile 1 (post-barrier; overlaps the stage latency).
    {
      const float sq2 = sq[colStart + 32 + c16];
      const float sq3 = sq[colStart + 48 + c16];
      const int dd = ((colStart + 32) - wRow) & 4095;
      if (dd < 64 || dd > 4064) {
#pragma unroll
        for (int mt = 0; mt < NMT; ++mt)
#pragma unroll
          for (int ct = 0; ct < 2; ++ct) {
            const float sqb = ct ? sq3 : sq2;
            const int lvc = dd + ct * 16 + c16 - q * 4;
#pragma unroll
            for (int r = 0; r < 4; ++r) {
              float v = fmaf(-2.f, acc[mt][ct][r], sqb);
              const int K = mt * 16 + r;
              if (lvc == K || lvc == K + 4096) v = __builtin_inff();
              minv[mt][r] = fminf(minv[mt][r], v);
            }
          }
      } else {
#pragma unroll
        for (int mt = 0; mt < NMT; ++mt)
#pragma unroll
          for (int ct = 0; ct < 2; ++ct) {
            const float sqb = ct ? sq3 : sq2;
#pragma unroll
            for (int r = 0; r < 4; ++r)
              minv[mt][r] = fminf(minv[mt][r], fmaf(-2.f, acc[mt][ct][r], sqb));
          }
      }
    }

    strip = strip + 1; if (strip >= NSTRIPS) strip -= NSTRIPS;
  }

  // Per-row finalize: reduce the 16 column-lanes, atomicMin (uint bits are
  // order-preserving for floats >= 0). Distinct addresses per row.
#pragma unroll
  for (int mt = 0; mt < NMT; ++mt)
#pragma unroll
    for (int r = 0; r < 4; ++r) {
      float v = minv[mt][r];
      v = fminf(v, __shfl_xor(v, 1));
      v = fminf(v, __shfl_xor(v, 2));
      v = fminf(v, __shfl_xor(v, 4));
      v = fminf(v, __shfl_xor(v, 8));
      if (c16 == 0) {
        const int row = wRow + mt * 16 + q * 4 + r;   // C/D: row=(lane>>4)*4+r
        float d2 = sq[row] + v;
        d2 = fmaxf(d2, 0.f);
        atomicMin(&negbits[row], __float_as_uint(d2));
      }
    }

  // ---- last-finishing block does the final scalar reduction ----
  __syncthreads();                 // all waves' atomics drained (vmcnt(0))
  if (tid == 0) {
    __threadfence();
    const unsigned int prev = atomicAdd(done, 1u);
    lastFlag = (prev == TOTAL_BLOCKS - 1) ? 1 : 0;
  }
  __syncthreads();                 // lastFlag is block-uniform
  if (lastFlag) {
    float s = 0.f, rg = 0.f;
    for (int i = tid; i < NROWS; i += 256) {
      const float pm = sqrtf(posmax2[i]);
      // Non-destructive coherent read: min(x, +inf) == x, returns old.
      const unsigned int nb2 = atomicMin(&negbits[i], 0x7F800000u);
      s += fmaxf(pm - sqrtf(__uint_as_float(nb2)) + 0.4f, 0.f);
    }
    for (int i = tid; i < BSZ; i += 256) rg += regpart[i];
    for (int m = 32; m; m >>= 1) { s += __shfl_xor(s, m); rg += __shfl_xor(rg, m); }
    if (lane == 0) { red[w] = s; redr[w] = rg; }
    __syncthreads();
    if (tid == 0) {
      const float t  = red[0] + red[1] + red[2] + red[3];
      const float tr = redr[0] + redr[1] + redr[2] + redr[3];
      out[0] = t / (float)NROWS + 0.01f * (tr / (float)(NROWS * DIM));
    }
  }
}

// ---------------------------------------------------------------------------
extern "C" void kernel_launch(void* const* d_in, const int* in_sizes, int n_in,
                              void* d_out, int out_size, void* d_ws, size_t ws_size,
                              hipStream_t stream) {
  const float* a  = (const float*)d_in[0];
  const float* p  = (const float*)d_in[1];
  const float* nn = (const float*)d_in[2];
  float* out = (float*)d_out;
  char* ws = (char*)d_ws;

  const size_t EMBH_BYTES = (size_t)NROWS * DIM * 2;       // 3,145,728
  unsigned short* embh    = (unsigned short*)ws;
  float*          sq      = (float*)(ws + EMBH_BYTES);
  unsigned int*   negbit  = (unsigned int*)(ws + EMBH_BYTES + (size_t)NROWS * 4);
  float*          pos2    = (float*)(ws + EMBH_BYTES + (size_t)NROWS * 8);
  float*          regpart = (float*)(ws + EMBH_BYTES + (size_t)NROWS * 12);
  unsigned int*   done    = (unsigned int*)(ws + EMBH_BYTES + (size_t)NROWS * 12 + (size_t)BSZ * 4);

  prep_k<<<BSZ / 4, 256, 0, stream>>>(a, p, nn, embh, sq, negbit, pos2, regpart, done);
  negmin_k<<<dim3(GRIDX, CSPLIT), 256, 0, stream>>>(embh, sq, negbit, pos2, regpart, done, out);
}

// Round 10
// 113.673 us; speedup vs baseline: 1.2828x; 1.1923x over previous
//
#include <hip/hip_runtime.h>

#define NROWS 12288
#define BSZ   4096
#define DIM   128
#define CSPLIT 16
#define COLS_PER_BLOCK (NROWS / CSPLIT)   // 768
#define NSTRIPS (COLS_PER_BLOCK / 32)     // 24 strips of 32 cols
#define ROWS_PER_BLOCK 192                // 4 waves x 48 rows
#define GRIDX (NROWS / ROWS_PER_BLOCK)    // 64
#define NMT 3                             // 16-row mtiles per wave

typedef __bf16 bf16x8 __attribute__((ext_vector_type(8)));
typedef float  f32x4  __attribute__((ext_vector_type(4)));

__device__ __forceinline__ unsigned short f2bf(float f) {
  unsigned int u = __float_as_uint(f);
  u = u + 0x7FFFu + ((u >> 16) & 1u);   // round-to-nearest-even
  return (unsigned short)(u >> 16);
}
__device__ __forceinline__ float bf2f(unsigned short h) {
  return __uint_as_float(((unsigned int)h) << 16);
}

// ---------------------------------------------------------------------------
// Kernel 1 (fused prep + posmax): one wave per triplet index i.
// ---------------------------------------------------------------------------
__global__ void prep_k(const float* __restrict__ a, const float* __restrict__ p,
                       const float* __restrict__ nn,
                       unsigned short* __restrict__ embh, float* __restrict__ sq,
                       unsigned int* __restrict__ negbits,
                       float* __restrict__ posmax2, float* __restrict__ regpart) {
  const int w = threadIdx.x >> 6, lane = threadIdx.x & 63;
  const int i = blockIdx.x * 4 + w;
  const float2 av = reinterpret_cast<const float2*>(a  + (size_t)i * DIM)[lane];
  const float2 pv = reinterpret_cast<const float2*>(p  + (size_t)i * DIM)[lane];
  const float2 nv = reinterpret_cast<const float2*>(nn + (size_t)i * DIM)[lane];

  const unsigned short ha0 = f2bf(av.x), ha1 = f2bf(av.y);
  const unsigned short hp0 = f2bf(pv.x), hp1 = f2bf(pv.y);
  const unsigned short hn0 = f2bf(nv.x), hn1 = f2bf(nv.y);
  reinterpret_cast<ushort2*>(embh + (size_t)i * DIM)[lane]             = make_ushort2(ha0, ha1);
  reinterpret_cast<ushort2*>(embh + (size_t)(BSZ + i) * DIM)[lane]     = make_ushort2(hp0, hp1);
  reinterpret_cast<ushort2*>(embh + (size_t)(2 * BSZ + i) * DIM)[lane] = make_ushort2(hn0, hn1);

  // sq of ROUNDED values (so the GEMM-based d2 is consistent & >= 0)
  float rax = bf2f(ha0), ray = bf2f(ha1);
  float rpx = bf2f(hp0), rpy = bf2f(hp1);
  float rnx = bf2f(hn0), rny = bf2f(hn1);
  float sa = rax * rax + ray * ray;
  float sp = rpx * rpx + rpy * rpy;
  float sn = rnx * rnx + rny * rny;

  // reg from exact values
  float t0 = fabsf(av.x) - 1.f, t1 = fabsf(av.y) - 1.f;
  float t2 = fabsf(pv.x) - 1.f, t3 = fabsf(pv.y) - 1.f;
  float t4 = fabsf(nv.x) - 1.f, t5 = fabsf(nv.y) - 1.f;
  float rg = t0 * t0 + t1 * t1 + t2 * t2 + t3 * t3 + t4 * t4 + t5 * t5;

  // pos distances, exact fp32
  float dx, dy;
  dx = av.x - pv.x; dy = av.y - pv.y; float dap = dx * dx + dy * dy;
  dx = av.x - nv.x; dy = av.y - nv.y; float dan = dx * dx + dy * dy;
  dx = pv.x - nv.x; dy = pv.y - nv.y; float dpn = dx * dx + dy * dy;

  for (int m = 32; m; m >>= 1) {
    sa  += __shfl_xor(sa, m);  sp  += __shfl_xor(sp, m);  sn  += __shfl_xor(sn, m);
    rg  += __shfl_xor(rg, m);
    dap += __shfl_xor(dap, m); dan += __shfl_xor(dan, m); dpn += __shfl_xor(dpn, m);
  }
  if (lane == 0) {
    sq[i] = sa; sq[BSZ + i] = sp; sq[2 * BSZ + i] = sn;
    negbits[i] = negbits[BSZ + i] = negbits[2 * BSZ + i] = 0x7F800000u;  // +inf
    posmax2[i]           = fmaxf(dap, dan);
    posmax2[BSZ + i]     = fmaxf(dap, dpn);
    posmax2[2 * BSZ + i] = fmaxf(dan, dpn);
    regpart[i] = rg;
  }
}

// ---------------------------------------------------------------------------
// Kernel 2: neg_min^2 = fused E*E^T (bf16 MFMA 16x16x32) + row-min.
// Round-10 = round-5's structure VERBATIM (32-col strips, double-buffered
// LDS, stage-after-barrier, epilogue-after-barrier, B consumed straight
// from LDS — the only profile that never spilled, 47.8 us) with ONE delta:
// waves shrink 64->48 rows (afrag 64->48), grid (64,16) = 1024 blocks =
// exactly 4 blocks/CU. r5's unified reg usage (~104) already fit 4
// waves/SIMD; its 768-block grid simply never requested the 4th block.
// 16 waves/CU attack the 60% idle that capped r5 at MfmaUtil 31%.
// (256,3): guaranteed >=3, natural allocation (~110 regs) permits 4.
// r6-r9 lesson: do NOT hold B in persistent registers; do NOT fuse the
// final reduction into this kernel.
// ---------------------------------------------------------------------------
__global__ __launch_bounds__(256, 3) void negmin_k(
    const unsigned short* __restrict__ embh,
    const float* __restrict__ sq,
    unsigned int* __restrict__ negbits) {
  __shared__ __align__(16) char ldsB[2][8192];   // [buf][chunk*1024 + lane*16]
  const int tid  = threadIdx.x;
  const int w    = tid >> 6;
  const int lane = tid & 63;
  const int c16  = lane & 15;
  const int q    = lane >> 4;
  const int wRow    = blockIdx.x * ROWS_PER_BLOCK + w * 48;  // wave's 48 rows
  const int colBase = blockIdx.y * COLS_PER_BLOCK;
  const int rot     = blockIdx.x % NSTRIPS;

  // A fragments: 48 rows x K=128. 3 mtiles x 4 ksteps, A[m=c16][k=q*8+j].
  bf16x8 afrag[NMT][4];
  {
    const char* abase = (const char*)embh + (size_t)(wRow + c16) * 256 + q * 16;
#pragma unroll
    for (int mt = 0; mt < NMT; ++mt)
#pragma unroll
      for (int ks = 0; ks < 4; ++ks)
        afrag[mt][ks] = *reinterpret_cast<const bf16x8*>(abase + mt * 4096 + ks * 64);
  }

  float minv[NMT][4];
#pragma unroll
  for (int mt = 0; mt < NMT; ++mt)
#pragma unroll
    for (int r = 0; r < 4; ++r) minv[mt][r] = __builtin_inff();

  // Stage a 32-col strip (8 KB) into LDS buffer b: 8 chunks of 1 KB, wave w
  // issues chunks 2w, 2w+1. Chunk (ks*2+ct) holds the B-fragment
  // B[k=q*8+j][n=ct*16+c16] for kstep ks at offset lane*16.
  auto stage = [&](int sidx, int b) {
#pragma unroll
    for (int h = 0; h < 2; ++h) {
      const int kc = w * 2 + h;
      const char* gp = (const char*)embh +
          (size_t)(colBase + sidx * 32 + (kc & 1) * 16 + c16) * 256 +
          (kc >> 1) * 64 + q * 16;
      __builtin_amdgcn_global_load_lds(
          (const __attribute__((address_space(1))) unsigned int*)gp,
          (__attribute__((address_space(3))) unsigned int*)(&ldsB[b][kc * 1024]),
          16, 0, 0);
    }
  };

  int strip = rot;                                   // strip index for iter c
  stage(strip, 0);
  { int s1 = strip + 1; if (s1 >= NSTRIPS) s1 -= NSTRIPS; stage(s1, 1); }
  __syncthreads();                                   // strips c=0,1 staged

  for (int c = 0; c < NSTRIPS; ++c) {
    const int b = c & 1;
    const char* lb = ldsB[b];
    const int colStart = colBase + strip * 32;
    const float sq0 = sq[colStart + c16];            // issued early, used post-barrier
    const float sq1 = sq[colStart + 16 + c16];

    f32x4 acc[NMT][2] = {};
#pragma unroll
    for (int f = 0; f < 8; ++f) {
      const int ks = f >> 1, ct = f & 1;
      const bf16x8 bb =
          *reinterpret_cast<const bf16x8*>(lb + f * 1024 + lane * 16);
#pragma unroll
      for (int mt = 0; mt < NMT; ++mt)
        acc[mt][ct] =
            __builtin_amdgcn_mfma_f32_16x16x32_bf16(afrag[mt][ks], bb, acc[mt][ct], 0, 0, 0);
    }

    // Barrier: all waves done reading buf b; drains each wave's own stage
    // loads issued last round; certifies buf b for overwrite.
    __syncthreads();
    if (c + 2 < NSTRIPS) {                           // stage strip c+2
      int s2 = strip + 2; if (s2 >= NSTRIPS) s2 -= NSTRIPS;
      stage(s2, b);
    }

    // Epilogue on registers (post-barrier; overlaps the stage latency).
    // Exclusion j == i (mod 4096): 48-row x 32-col tile -> only when
    // dd in [0,64) U (4048,4095] (superset; inner test is exact).
    const int dd = (colStart - wRow) & 4095;
    if (dd < 64 || dd > 4048) {
#pragma unroll
      for (int mt = 0; mt < NMT; ++mt)
#pragma unroll
        for (int ct = 0; ct < 2; ++ct) {
          const float sqb = ct ? sq1 : sq0;
          const int lvc = dd + ct * 16 + c16 - q * 4;
#pragma unroll
          for (int r = 0; r < 4; ++r) {
            float v = fmaf(-2.f, acc[mt][ct][r], sqb);
            const int K = mt * 16 + r;
            if (lvc == K || lvc == K + 4096) v = __builtin_inff();
            minv[mt][r] = fminf(minv[mt][r], v);
          }
        }
    } else {
#pragma unroll
      for (int mt = 0; mt < NMT; ++mt)
#pragma unroll
        for (int ct = 0; ct < 2; ++ct) {
          const float sqb = ct ? sq1 : sq0;
#pragma unroll
          for (int r = 0; r < 4; ++r)
            minv[mt][r] = fminf(minv[mt][r], fmaf(-2.f, acc[mt][ct][r], sqb));
        }
    }

    strip = strip + 1; if (strip >= NSTRIPS) strip -= NSTRIPS;
  }

  // Per-row finalize: reduce the 16 column-lanes, atomicMin (uint bits are
  // order-preserving for floats >= 0). Distinct addresses per row.
#pragma unroll
  for (int mt = 0; mt < NMT; ++mt)
#pragma unroll
    for (int r = 0; r < 4; ++r) {
      float v = minv[mt][r];
      v = fminf(v, __shfl_xor(v, 1));
      v = fminf(v, __shfl_xor(v, 2));
      v = fminf(v, __shfl_xor(v, 4));
      v = fminf(v, __shfl_xor(v, 8));
      if (c16 == 0) {
        const int row = wRow + mt * 16 + q * 4 + r;   // C/D: row=(lane>>4)*4+r
        float d2 = sq[row] + v;
        d2 = fmaxf(d2, 0.f);
        atomicMin(&negbits[row], __float_as_uint(d2));
      }
    }
}

// ---------------------------------------------------------------------------
// Kernel 3: final scalar reduction. Single block, 1024 threads.
// ---------------------------------------------------------------------------
__global__ void final_k(const float* __restrict__ posmax2,
                        const unsigned int* __restrict__ negbits,
                        const float* __restrict__ regpart, float* __restrict__ out) {
  __shared__ float red[16], redr[16];
  const int tid = threadIdx.x;  // 1024
  float s = 0.f;
  for (int i = tid; i < NROWS; i += 1024) {
    const float pm = sqrtf(posmax2[i]);
    const float nm = sqrtf(__uint_as_float(negbits[i]));
    s += fmaxf(pm - nm + 0.4f, 0.f);
  }
  float rg = 0.f;
  for (int i = tid; i < BSZ; i += 1024) rg += regpart[i];
  for (int m = 32; m; m >>= 1) { s += __shfl_xor(s, m); rg += __shfl_xor(rg, m); }
  if ((tid & 63) == 0) { red[tid >> 6] = s; redr[tid >> 6] = rg; }
  __syncthreads();
  if (tid == 0) {
    float t = 0.f, tr = 0.f;
#pragma unroll
    for (int k = 0; k < 16; ++k) { t += red[k]; tr += redr[k]; }
    out[0] = t / (float)NROWS + 0.01f * (tr / (float)(NROWS * DIM));
  }
}

// ---------------------------------------------------------------------------
extern "C" void kernel_launch(void* const* d_in, const int* in_sizes, int n_in,
                              void* d_out, int out_size, void* d_ws, size_t ws_size,
                              hipStream_t stream) {
  const float* a  = (const float*)d_in[0];
  const float* p  = (const float*)d_in[1];
  const float* nn = (const float*)d_in[2];
  float* out = (float*)d_out;
  char* ws = (char*)d_ws;

  const size_t EMBH_BYTES = (size_t)NROWS * DIM * 2;       // 3,145,728
  unsigned short* embh    = (unsigned short*)ws;
  float*          sq      = (float*)(ws + EMBH_BYTES);
  unsigned int*   negbit  = (unsigned int*)(ws + EMBH_BYTES + (size_t)NROWS * 4);
  float*          pos2    = (float*)(ws + EMBH_BYTES + (size_t)NROWS * 8);
  float*          regpart = (float*)(ws + EMBH_BYTES + (size_t)NROWS * 12);

  prep_k<<<BSZ / 4, 256, 0, stream>>>(a, p, nn, embh, sq, negbit, pos2, regpart);
  negmin_k<<<dim3(GRIDX, CSPLIT), 256, 0, stream>>>(embh, sq, negbit);
  final_k<<<1, 1024, 0, stream>>>(pos2, negbit, regpart, out);
}